// Round 1
// baseline (178.677 us; speedup 1.0000x reference)
//
#include <hip/hip_runtime.h>
#include <hip/hip_bf16.h>

typedef __bf16 bf16_t;
typedef __bf16 bf16x8 __attribute__((ext_vector_type(8)));
typedef __bf16 bf16x4 __attribute__((ext_vector_type(4)));
typedef float  f32x4  __attribute__((ext_vector_type(4)));

#define MFMA16(a, b, c) __builtin_amdgcn_mfma_f32_16x16x32_bf16((a), (b), (c), 0, 0, 0)

// ---------------------------------------------------------------------------
// K0: cast weights fp32 -> bf16.  Wqkv = [wq; wk; wv] (1536 x 512), Wp (512x512)
// grid: 256 blocks x 256 threads, 4 elems/thread  (512*512 = 262144)
// ---------------------------------------------------------------------------
__global__ __launch_bounds__(256) void cast_weights(
    const float* __restrict__ wq, const float* __restrict__ wk,
    const float* __restrict__ wv, const float* __restrict__ wp,
    bf16_t* __restrict__ Wqkv, bf16_t* __restrict__ Wp)
{
    const int i = (blockIdx.x * 256 + threadIdx.x) * 4;
#pragma unroll
    for (int j = 0; j < 4; ++j) {
        Wqkv[i + j]          = (bf16_t)wq[i + j];
        Wqkv[262144 + i + j] = (bf16_t)wk[i + j];
        Wqkv[524288 + i + j] = (bf16_t)wv[i + j];
        Wp[i + j]            = (bf16_t)wp[i + j];
    }
}

// ---------------------------------------------------------------------------
// K1: GroupNorm.  One block per (b, group): 16 channels x 1024 spatial.
// Writes xnT[(b*1024+n)*512 + c]  (bf16, n-major -> k-contiguous for GEMM B-op)
// ---------------------------------------------------------------------------
__global__ __launch_bounds__(256) void gn_kernel(
    const float* __restrict__ x, const float* __restrict__ gamma,
    const float* __restrict__ beta, bf16_t* __restrict__ xnT)
{
    const int blk = blockIdx.x;
    const int b = blk >> 5, g = blk & 31;
    const int t = threadIdx.x;
    __shared__ float red[8];
    const float* base = x + ((size_t)b * 512 + g * 16) * 1024;

    float s = 0.f, s2 = 0.f;
    for (int i = t; i < 16384; i += 256) {   // i = c*1024 + n : coalesced
        float v = base[i];
        s += v; s2 += v * v;
    }
#pragma unroll
    for (int m = 1; m < 64; m <<= 1) { s += __shfl_xor(s, m); s2 += __shfl_xor(s2, m); }
    const int w = t >> 6;
    if ((t & 63) == 0) { red[w] = s; red[4 + w] = s2; }
    __syncthreads();
    s  = red[0] + red[1] + red[2] + red[3];
    s2 = red[4] + red[5] + red[6] + red[7];
    const float mean = s * (1.f / 16384.f);
    const float var  = fmaxf(s2 * (1.f / 16384.f) - mean * mean, 0.f);
    const float rstd = rsqrtf(var + 1e-6f);

    for (int i = t; i < 16384; i += 256) {
        const int n = i >> 4, c = i & 15;
        const float v = base[c * 1024 + n];       // L2-hit (streamed in pass 1)
        const int gc = g * 16 + c;
        const float y = (v - mean) * rstd * gamma[gc] + beta[gc];
        xnT[((size_t)b * 1024 + n) * 512 + gc] = (bf16_t)y;
    }
}

// ---------------------------------------------------------------------------
// K2/K4: GEMM  C[m][n'] = sum_k A[m][k] * Bt[n'][k],  K = 512, N' = 8192.
// 128x128 tile, BK=32, 4 waves (2x2), each wave 64x64 via 4x4 16x16x32 MFMA.
// mode 0: QKV epilogue (+bias, scatter to Q/K [bh][n][d] and V [bh][d][n])
// mode 1: proj epilogue (+bproj + x0 residual, fp32 out [b][c][n])
// ---------------------------------------------------------------------------
__global__ __launch_bounds__(256) void gemm_bt(
    const bf16_t* __restrict__ A, const bf16_t* __restrict__ Bt, int mode,
    const float* __restrict__ bias0, const float* __restrict__ bias1,
    const float* __restrict__ bias2,
    const float* __restrict__ x0, float* __restrict__ outF,
    bf16_t* __restrict__ Qb, bf16_t* __restrict__ Kb, bf16_t* __restrict__ Vb)
{
    const int K  = 512;
    const int m0 = blockIdx.x * 128;
    const int n0 = blockIdx.y * 128;
    const int t = threadIdx.x;
    const int l = t & 63, w = t >> 6;
    const int wr = w >> 1, wc = w & 1;
    const int lrow = l & 15, lgrp = l >> 4;

    __shared__ __align__(16) bf16_t As[128][40];   // +8 pad
    __shared__ __align__(16) bf16_t Bs[128][40];

    f32x4 acc[4][4];
#pragma unroll
    for (int i = 0; i < 4; ++i)
#pragma unroll
        for (int j = 0; j < 4; ++j) acc[i][j] = (f32x4){0.f, 0.f, 0.f, 0.f};

    const int sr = t >> 2;          // 0..63
    const int sc = (t & 3) * 8;     // 0,8,16,24
    const bf16_t* Arow0 = A  + (size_t)(m0 + sr) * K + sc;
    const bf16_t* Arow1 = A  + (size_t)(m0 + 64 + sr) * K + sc;
    const bf16_t* Brow0 = Bt + (size_t)(n0 + sr) * K + sc;
    const bf16_t* Brow1 = Bt + (size_t)(n0 + 64 + sr) * K + sc;

    for (int k0 = 0; k0 < K; k0 += 32) {
        bf16x8 a0 = *(const bf16x8*)(Arow0 + k0);
        bf16x8 a1 = *(const bf16x8*)(Arow1 + k0);
        bf16x8 b0 = *(const bf16x8*)(Brow0 + k0);
        bf16x8 b1 = *(const bf16x8*)(Brow1 + k0);
        __syncthreads();
        *(bf16x8*)&As[sr][sc]      = a0;
        *(bf16x8*)&As[64 + sr][sc] = a1;
        *(bf16x8*)&Bs[sr][sc]      = b0;
        *(bf16x8*)&Bs[64 + sr][sc] = b1;
        __syncthreads();
        bf16x8 af[4], bfr[4];
#pragma unroll
        for (int ms = 0; ms < 4; ++ms)
            af[ms] = *(const bf16x8*)&As[wr * 64 + ms * 16 + lrow][lgrp * 8];
#pragma unroll
        for (int ns = 0; ns < 4; ++ns)
            bfr[ns] = *(const bf16x8*)&Bs[wc * 64 + ns * 16 + lrow][lgrp * 8];
#pragma unroll
        for (int ms = 0; ms < 4; ++ms)
#pragma unroll
            for (int ns = 0; ns < 4; ++ns)
                acc[ms][ns] = MFMA16(af[ms], bfr[ns], acc[ms][ns]);
    }

    if (mode == 0) {
        const int which = m0 >> 9;    // 0=q 1=k 2=v  (uniform per block)
        const float* bias = (which == 0) ? bias0 : (which == 1) ? bias1 : bias2;
        bf16_t* Qk = (which == 0) ? Qb : Kb;
#pragma unroll
        for (int ms = 0; ms < 4; ++ms) {
#pragma unroll
            for (int ns = 0; ns < 4; ++ns) {
                const int gm = m0 + wr * 64 + ms * 16 + lgrp * 4;
                const int o  = gm & 511;
                const int hh = o >> 6, db = o & 63;
                const int np = n0 + wc * 64 + ns * 16 + lrow;
                const int b = np >> 10, n = np & 1023;
                if (which < 2) {
                    bf16x4 pk;
#pragma unroll
                    for (int j = 0; j < 4; ++j)
                        pk[j] = (bf16_t)(acc[ms][ns][j] + bias[o + j]);
                    *(bf16x4*)(Qk + (((size_t)b * 8 + hh) * 1024 + n) * 64 + db) = pk;
                } else {
#pragma unroll
                    for (int j = 0; j < 4; ++j)
                        Vb[(((size_t)b * 8 + hh) * 64 + db + j) * 1024 + n] =
                            (bf16_t)(acc[ms][ns][j] + bias[o + j]);
                }
            }
        }
    } else {
#pragma unroll
        for (int ms = 0; ms < 4; ++ms) {
#pragma unroll
            for (int ns = 0; ns < 4; ++ns) {
                const int c  = m0 + wr * 64 + ms * 16 + lgrp * 4;
                const int np = n0 + wc * 64 + ns * 16 + lrow;
                const int b = np >> 10, n = np & 1023;
#pragma unroll
                for (int j = 0; j < 4; ++j) {
                    const size_t idx = ((size_t)b * 512 + c + j) * 1024 + n;
                    outF[idx] = acc[ms][ns][j] + bias0[c + j] + x0[idx];
                }
            }
        }
    }
}

// ---------------------------------------------------------------------------
// K3: fused attention.  Block = (q-tile of 64) x (b,h).  4 waves, each owns
// 16 q rows.  KV tiles of 64 staged in LDS; online softmax; rel-bias from
// LDS-staged bf16 pos_enc with REL_IDX computed inline.
// Writes XoT[(b*1024+q)*512 + h*64 + d]  (bf16, k-contiguous for proj GEMM).
// ---------------------------------------------------------------------------
__global__ __launch_bounds__(256) void attn_kernel(
    const bf16_t* __restrict__ Qb, const bf16_t* __restrict__ Kb,
    const bf16_t* __restrict__ Vb, const float* __restrict__ pos,
    bf16_t* __restrict__ Xo)
{
    const int bh = blockIdx.y;
    const int h  = bh & 7;
    const int q0 = blockIdx.x * 64;
    const int t = threadIdx.x;
    const int w = t >> 6, l = t & 63;
    const int lrow = l & 15, lgrp = l >> 4;

    __shared__ __align__(16) bf16_t Ks[64][72];      // [nk][d], +8 pad
    __shared__ __align__(16) bf16_t Vs[64][72];      // [d][nk], +8 pad
    __shared__ __align__(16) bf16_t Ps[4][16][72];   // per-wave [q][nk]
    __shared__ bf16_t pos_s[3969];

    for (int i = t; i < 3969; i += 256) pos_s[i] = (bf16_t)pos[h * 3969 + i];

    // Q fragments: A-op, row = lane&15, 8 consecutive d per lane-group
    const int qrow = q0 + w * 16 + lrow;
    const bf16_t* qbase = Qb + ((size_t)bh * 1024 + qrow) * 64;
    const bf16x8 qf0 = *(const bf16x8*)(qbase + lgrp * 8);
    const bf16x8 qf1 = *(const bf16x8*)(qbase + 32 + lgrp * 8);

    float rm[4], rl[4];
    f32x4 oacc[4];
#pragma unroll
    for (int j = 0; j < 4; ++j) { rm[j] = -3e38f; rl[j] = 0.f; oacc[j] = (f32x4){0.f,0.f,0.f,0.f}; }

    const int sr_ = t >> 2;         // 0..63
    const int sc_ = (t & 3) * 8;    // 0,8,16,24
    const bf16_t* Krow = Kb + ((size_t)bh * 1024 + sr_) * 64 + sc_;
    const bf16_t* Vrow = Vb + ((size_t)bh * 64 + sr_) * 1024 + sc_;

    for (int kt = 0; kt < 16; ++kt) {
        const int nk0 = kt * 64;
        bf16x8 kv0 = *(const bf16x8*)(Krow + (size_t)nk0 * 64);
        bf16x8 kv1 = *(const bf16x8*)(Krow + (size_t)nk0 * 64 + 32);
        bf16x8 vv0 = *(const bf16x8*)(Vrow + nk0);
        bf16x8 vv1 = *(const bf16x8*)(Vrow + nk0 + 32);
        __syncthreads();
        *(bf16x8*)&Ks[sr_][sc_]      = kv0;
        *(bf16x8*)&Ks[sr_][sc_ + 32] = kv1;
        *(bf16x8*)&Vs[sr_][sc_]      = vv0;
        *(bf16x8*)&Vs[sr_][sc_ + 32] = vv1;
        __syncthreads();

        // S = Q K^T   (D rows = q, cols = nk)
        f32x4 s[4];
#pragma unroll
        for (int ns = 0; ns < 4; ++ns) {
            bf16x8 kf0 = *(const bf16x8*)&Ks[ns * 16 + lrow][lgrp * 8];
            bf16x8 kf1 = *(const bf16x8*)&Ks[ns * 16 + lrow][32 + lgrp * 8];
            f32x4 z = (f32x4){0.f, 0.f, 0.f, 0.f};
            z = MFMA16(qf0, kf0, z);
            z = MFMA16(qf1, kf1, z);
            s[ns] = z;
        }
        // logits = S*scale + rel_bias ; tile max
        float lgt[4][4];
        float tmax[4] = {-3e38f, -3e38f, -3e38f, -3e38f};
#pragma unroll
        for (int ns = 0; ns < 4; ++ns) {
            const int nk = nk0 + ns * 16 + lrow;
            const int ky = nk >> 5, kx = nk & 31;
#pragma unroll
            for (int j = 0; j < 4; ++j) {
                const int q = q0 + w * 16 + lgrp * 4 + j;
                const int dy = (q >> 5) - ky + 31, dx = (q & 31) - kx + 31;
                const float bias = (float)pos_s[dy * 63 + dx];
                const float v = s[ns][j] * 0.125f + bias;
                lgt[ns][j] = v;
                tmax[j] = fmaxf(tmax[j], v);
            }
        }
#pragma unroll
        for (int j = 0; j < 4; ++j) {
            float v = tmax[j];
            v = fmaxf(v, __shfl_xor(v, 1));
            v = fmaxf(v, __shfl_xor(v, 2));
            v = fmaxf(v, __shfl_xor(v, 4));
            v = fmaxf(v, __shfl_xor(v, 8));
            tmax[j] = v;
        }
        float rf[4], ts[4];
#pragma unroll
        for (int j = 0; j < 4; ++j) {
            const float mn = fmaxf(rm[j], tmax[j]);
            rf[j] = __expf(rm[j] - mn);
            rm[j] = mn;
            ts[j] = 0.f;
        }
        // P = exp(logit - m), store to per-wave LDS in [q][nk] layout
#pragma unroll
        for (int ns = 0; ns < 4; ++ns)
#pragma unroll
            for (int j = 0; j < 4; ++j) {
                const float p = __expf(lgt[ns][j] - rm[j]);
                ts[j] += p;
                Ps[w][lgrp * 4 + j][ns * 16 + lrow] = (bf16_t)p;
            }
#pragma unroll
        for (int j = 0; j < 4; ++j) {
            float v = ts[j];
            v += __shfl_xor(v, 1);
            v += __shfl_xor(v, 2);
            v += __shfl_xor(v, 4);
            v += __shfl_xor(v, 8);
            rl[j] = rl[j] * rf[j] + v;
#pragma unroll
            for (int ds = 0; ds < 4; ++ds) oacc[ds][j] *= rf[j];
        }
        // PV: A = P (row=q, k=nk), B = V^T (col=d, k=nk)
        const bf16x8 pf0 = *(const bf16x8*)&Ps[w][lrow][lgrp * 8];
        const bf16x8 pf1 = *(const bf16x8*)&Ps[w][lrow][32 + lgrp * 8];
#pragma unroll
        for (int ds = 0; ds < 4; ++ds) {
            bf16x8 vf0 = *(const bf16x8*)&Vs[ds * 16 + lrow][lgrp * 8];
            bf16x8 vf1 = *(const bf16x8*)&Vs[ds * 16 + lrow][32 + lgrp * 8];
            oacc[ds] = MFMA16(pf0, vf0, oacc[ds]);
            oacc[ds] = MFMA16(pf1, vf1, oacc[ds]);
        }
    }

    const int b = bh >> 3;
#pragma unroll
    for (int ds = 0; ds < 4; ++ds) {
#pragma unroll
        for (int j = 0; j < 4; ++j) {
            const float val = oacc[ds][j] / rl[j];
            const int q = q0 + w * 16 + lgrp * 4 + j;
            const int d = ds * 16 + lrow;
            Xo[((size_t)b * 1024 + q) * 512 + h * 64 + d] = (bf16_t)val;
        }
    }
}

// ---------------------------------------------------------------------------
extern "C" void kernel_launch(void* const* d_in, const int* in_sizes, int n_in,
                              void* d_out, int out_size, void* d_ws, size_t ws_size,
                              hipStream_t stream)
{
    const float* x     = (const float*)d_in[0];
    const float* gamma = (const float*)d_in[3];
    const float* beta  = (const float*)d_in[4];
    const float* wq    = (const float*)d_in[5];
    const float* bq    = (const float*)d_in[6];
    const float* wk    = (const float*)d_in[7];
    const float* bk    = (const float*)d_in[8];
    const float* wv    = (const float*)d_in[9];
    const float* bv    = (const float*)d_in[10];
    const float* wp    = (const float*)d_in[11];
    const float* bp    = (const float*)d_in[12];
    const float* pos   = (const float*)d_in[13];
    float* out = (float*)d_out;

    char* ws = (char*)d_ws;
    bf16_t* Wqkv = (bf16_t*)ws; ws += (size_t)1536 * 512 * 2;
    bf16_t* Wp   = (bf16_t*)ws; ws += (size_t)512 * 512 * 2;
    bf16_t* xnT  = (bf16_t*)ws; ws += (size_t)8192 * 512 * 2;
    bf16_t* Qb   = (bf16_t*)ws; ws += (size_t)8192 * 512 * 2;
    bf16_t* Kb   = (bf16_t*)ws; ws += (size_t)8192 * 512 * 2;
    bf16_t* Vb   = (bf16_t*)ws; ws += (size_t)8192 * 512 * 2;
    bf16_t* Xo   = (bf16_t*)ws; ws += (size_t)8192 * 512 * 2;

    hipLaunchKernelGGL(cast_weights, dim3(256), dim3(256), 0, stream,
                       wq, wk, wv, wp, Wqkv, Wp);
    hipLaunchKernelGGL(gn_kernel, dim3(256), dim3(256), 0, stream,
                       x, gamma, beta, xnT);
    hipLaunchKernelGGL(gemm_bt, dim3(12, 64), dim3(256), 0, stream,
                       Wqkv, xnT, 0, bq, bk, bv,
                       nullptr, nullptr, Qb, Kb, Vb);
    hipLaunchKernelGGL(attn_kernel, dim3(16, 64), dim3(256), 0, stream,
                       Qb, Kb, Vb, pos, Xo);
    hipLaunchKernelGGL(gemm_bt, dim3(4, 64), dim3(256), 0, stream,
                       Wp, Xo, 1, bp, nullptr, nullptr,
                       x, out, nullptr, nullptr, nullptr);
}

// Round 2
// 171.990 us; speedup vs baseline: 1.0389x; 1.0389x over previous
//
#include <hip/hip_runtime.h>
#include <hip/hip_bf16.h>

typedef __bf16 bf16_t;
typedef __bf16 bf16x8 __attribute__((ext_vector_type(8)));
typedef __bf16 bf16x4 __attribute__((ext_vector_type(4)));
typedef float  f32x4  __attribute__((ext_vector_type(4)));

#define MFMA16(a, b, c) __builtin_amdgcn_mfma_f32_16x16x32_bf16((a), (b), (c), 0, 0, 0)

// ---------------------------------------------------------------------------
// K0: cast weights fp32 -> bf16.  Wqkv = [wq; wk; wv] (1536 x 512), Wp (512x512)
// ---------------------------------------------------------------------------
__global__ __launch_bounds__(256) void cast_weights(
    const float* __restrict__ wq, const float* __restrict__ wk,
    const float* __restrict__ wv, const float* __restrict__ wp,
    bf16_t* __restrict__ Wqkv, bf16_t* __restrict__ Wp)
{
    const int i = (blockIdx.x * 256 + threadIdx.x) * 4;
#pragma unroll
    for (int j = 0; j < 4; ++j) {
        Wqkv[i + j]          = (bf16_t)wq[i + j];
        Wqkv[262144 + i + j] = (bf16_t)wk[i + j];
        Wqkv[524288 + i + j] = (bf16_t)wv[i + j];
        Wp[i + j]            = (bf16_t)wp[i + j];
    }
}

// ---------------------------------------------------------------------------
// K0b: rel-bias precompute, laid out in MFMA C-fragment order:
//   Bias2[h][qt(64)][kt(64)][lane(64)][j(4)]  bf16
// where q = qt*16 + (lane>>4)*4 + j,  nk = kt*16 + (lane&15),
// val = pos[h][(qy-ky+31)*63 + (qx-kx+31)].
// Block = (h, qt): qy = qt>>1 fixed; stages the 32 needed pos rows in LDS.
// ---------------------------------------------------------------------------
__global__ __launch_bounds__(256) void bias_kernel(
    const float* __restrict__ pos, bf16_t* __restrict__ Bias2)
{
    const int h   = blockIdx.x >> 6;
    const int qt  = blockIdx.x & 63;
    const int qy  = qt >> 1;
    const int qxb = (qt & 1) * 16;
    const int t = threadIdx.x;
    __shared__ bf16_t ps[32][64];   // rows dy = qy..qy+31, cols dx 0..62

    for (int i = t; i < 32 * 63; i += 256) {
        const int r = i / 63, dx = i - r * 63;
        ps[r][dx] = (bf16_t)pos[h * 3969 + (qy + r) * 63 + dx];
    }
    __syncthreads();

    bf16_t* outb = Bias2 + (((size_t)h * 64 + qt) * 64) * 256;  // *64 lanes *4 j
#pragma unroll
    for (int it = 0; it < 16; ++it) {
        const int idx = t + it * 256;        // [0, 4096)
        const int kt = idx >> 6, l = idx & 63;
        const int nk = kt * 16 + (l & 15);
        const int ky = nk >> 5, kx = nk & 31;
        const int qx0 = qxb + (l >> 4) * 4;
        const int r = 31 - ky;
        const int dx0 = qx0 - kx + 31;
        bf16x4 o;
#pragma unroll
        for (int j = 0; j < 4; ++j) o[j] = ps[r][dx0 + j];
        *(bf16x4*)(outb + (size_t)idx * 4) = o;
    }
}

// ---------------------------------------------------------------------------
// K1: GroupNorm -> xnT[(b*1024+n)*512 + c]  (bf16, k-contiguous for GEMM)
// ---------------------------------------------------------------------------
__global__ __launch_bounds__(256) void gn_kernel(
    const float* __restrict__ x, const float* __restrict__ gamma,
    const float* __restrict__ beta, bf16_t* __restrict__ xnT)
{
    const int blk = blockIdx.x;
    const int b = blk >> 5, g = blk & 31;
    const int t = threadIdx.x;
    __shared__ float red[8];
    const float* base = x + ((size_t)b * 512 + g * 16) * 1024;

    float s = 0.f, s2 = 0.f;
    for (int i = t; i < 16384; i += 256) {
        float v = base[i];
        s += v; s2 += v * v;
    }
#pragma unroll
    for (int m = 1; m < 64; m <<= 1) { s += __shfl_xor(s, m); s2 += __shfl_xor(s2, m); }
    const int w = t >> 6;
    if ((t & 63) == 0) { red[w] = s; red[4 + w] = s2; }
    __syncthreads();
    s  = red[0] + red[1] + red[2] + red[3];
    s2 = red[4] + red[5] + red[6] + red[7];
    const float mean = s * (1.f / 16384.f);
    const float var  = fmaxf(s2 * (1.f / 16384.f) - mean * mean, 0.f);
    const float rstd = rsqrtf(var + 1e-6f);

    for (int i = t; i < 16384; i += 256) {
        const int n = i >> 4, c = i & 15;
        const float v = base[c * 1024 + n];
        const int gc = g * 16 + c;
        const float y = (v - mean) * rstd * gamma[gc] + beta[gc];
        xnT[((size_t)b * 1024 + n) * 512 + gc] = (bf16_t)y;
    }
}

// ---------------------------------------------------------------------------
// K2/K4: GEMM  C[m][n'] = sum_k A[m][k] * Bt[n'][k],  K = 512, N' = 8192.
// mode 0: QKV epilogue (+bias; Q pre-scaled by 0.125; scatter Q/K/V)
// mode 1: proj epilogue (+bproj + x0 residual, fp32 out)
// ---------------------------------------------------------------------------
__global__ __launch_bounds__(256) void gemm_bt(
    const bf16_t* __restrict__ A, const bf16_t* __restrict__ Bt, int mode,
    const float* __restrict__ bias0, const float* __restrict__ bias1,
    const float* __restrict__ bias2,
    const float* __restrict__ x0, float* __restrict__ outF,
    bf16_t* __restrict__ Qb, bf16_t* __restrict__ Kb, bf16_t* __restrict__ Vb)
{
    const int K  = 512;
    const int m0 = blockIdx.x * 128;
    const int n0 = blockIdx.y * 128;
    const int t = threadIdx.x;
    const int l = t & 63, w = t >> 6;
    const int wr = w >> 1, wc = w & 1;
    const int lrow = l & 15, lgrp = l >> 4;

    __shared__ __align__(16) bf16_t As[128][40];
    __shared__ __align__(16) bf16_t Bs[128][40];

    f32x4 acc[4][4];
#pragma unroll
    for (int i = 0; i < 4; ++i)
#pragma unroll
        for (int j = 0; j < 4; ++j) acc[i][j] = (f32x4){0.f, 0.f, 0.f, 0.f};

    const int sr = t >> 2;
    const int sc = (t & 3) * 8;
    const bf16_t* Arow0 = A  + (size_t)(m0 + sr) * K + sc;
    const bf16_t* Arow1 = A  + (size_t)(m0 + 64 + sr) * K + sc;
    const bf16_t* Brow0 = Bt + (size_t)(n0 + sr) * K + sc;
    const bf16_t* Brow1 = Bt + (size_t)(n0 + 64 + sr) * K + sc;

    for (int k0 = 0; k0 < K; k0 += 32) {
        bf16x8 a0 = *(const bf16x8*)(Arow0 + k0);
        bf16x8 a1 = *(const bf16x8*)(Arow1 + k0);
        bf16x8 b0 = *(const bf16x8*)(Brow0 + k0);
        bf16x8 b1 = *(const bf16x8*)(Brow1 + k0);
        __syncthreads();
        *(bf16x8*)&As[sr][sc]      = a0;
        *(bf16x8*)&As[64 + sr][sc] = a1;
        *(bf16x8*)&Bs[sr][sc]      = b0;
        *(bf16x8*)&Bs[64 + sr][sc] = b1;
        __syncthreads();
        bf16x8 af[4], bfr[4];
#pragma unroll
        for (int ms = 0; ms < 4; ++ms)
            af[ms] = *(const bf16x8*)&As[wr * 64 + ms * 16 + lrow][lgrp * 8];
#pragma unroll
        for (int ns = 0; ns < 4; ++ns)
            bfr[ns] = *(const bf16x8*)&Bs[wc * 64 + ns * 16 + lrow][lgrp * 8];
#pragma unroll
        for (int ms = 0; ms < 4; ++ms)
#pragma unroll
            for (int ns = 0; ns < 4; ++ns)
                acc[ms][ns] = MFMA16(af[ms], bfr[ns], acc[ms][ns]);
    }

    if (mode == 0) {
        const int which = m0 >> 9;    // 0=q 1=k 2=v
        const float* bias = (which == 0) ? bias0 : (which == 1) ? bias1 : bias2;
        bf16_t* Qk = (which == 0) ? Qb : Kb;
        const float scl = (which == 0) ? 0.125f : 1.0f;   // fold 1/sqrt(64) into Q
#pragma unroll
        for (int ms = 0; ms < 4; ++ms) {
#pragma unroll
            for (int ns = 0; ns < 4; ++ns) {
                const int gm = m0 + wr * 64 + ms * 16 + lgrp * 4;
                const int o  = gm & 511;
                const int hh = o >> 6, db = o & 63;
                const int np = n0 + wc * 64 + ns * 16 + lrow;
                const int b = np >> 10, n = np & 1023;
                if (which < 2) {
                    bf16x4 pk;
#pragma unroll
                    for (int j = 0; j < 4; ++j)
                        pk[j] = (bf16_t)((acc[ms][ns][j] + bias[o + j]) * scl);
                    *(bf16x4*)(Qk + (((size_t)b * 8 + hh) * 1024 + n) * 64 + db) = pk;
                } else {
#pragma unroll
                    for (int j = 0; j < 4; ++j)
                        Vb[(((size_t)b * 8 + hh) * 64 + db + j) * 1024 + n] =
                            (bf16_t)(acc[ms][ns][j] + bias[o + j]);
                }
            }
        }
    } else {
#pragma unroll
        for (int ms = 0; ms < 4; ++ms) {
#pragma unroll
            for (int ns = 0; ns < 4; ++ns) {
                const int c  = m0 + wr * 64 + ms * 16 + lgrp * 4;
                const int np = n0 + wc * 64 + ns * 16 + lrow;
                const int b = np >> 10, n = np & 1023;
#pragma unroll
                for (int j = 0; j < 4; ++j) {
                    const size_t idx = ((size_t)b * 512 + c + j) * 1024 + n;
                    outF[idx] = acc[ms][ns][j] + bias0[c + j] + x0[idx];
                }
            }
        }
    }
}

// ---------------------------------------------------------------------------
// K3: fused attention.  PRE=1: bias from Bias2 via MFMA C-init; Q pre-scaled.
// PRE=0: legacy pos_s gather fallback (if ws too small for Bias2).
// ---------------------------------------------------------------------------
template <int PRE>
__global__ __launch_bounds__(256) void attn_kernel(
    const bf16_t* __restrict__ Qb, const bf16_t* __restrict__ Kb,
    const bf16_t* __restrict__ Vb, const float* __restrict__ pos,
    const bf16_t* __restrict__ Bias2, bf16_t* __restrict__ Xo)
{
    const int bh = blockIdx.y;
    const int h  = bh & 7;
    const int q0 = blockIdx.x * 64;
    const int t = threadIdx.x;
    const int w = t >> 6, l = t & 63;
    const int lrow = l & 15, lgrp = l >> 4;

    __shared__ __align__(16) bf16_t Ks[64][72];
    __shared__ __align__(16) bf16_t Vs[64][72];
    __shared__ __align__(16) bf16_t Ps[4][16][72];
    __shared__ bf16_t pos_s[PRE ? 1 : 3969];

    if (!PRE)
        for (int i = t; i < 3969; i += 256) pos_s[i] = (bf16_t)pos[h * 3969 + i];

    const int qrow = q0 + w * 16 + lrow;
    const bf16_t* qbase = Qb + ((size_t)bh * 1024 + qrow) * 64;
    const bf16x8 qf0 = *(const bf16x8*)(qbase + lgrp * 8);
    const bf16x8 qf1 = *(const bf16x8*)(qbase + 32 + lgrp * 8);

    // per-wave bias fragment base: qt = q0/16 + w
    const bf16_t* bb = Bias2 + (((size_t)h * 64 + (q0 >> 4) + w) * 64) * 256;

    float rm[4], rl[4];
    f32x4 oacc[4];
#pragma unroll
    for (int j = 0; j < 4; ++j) { rm[j] = -3e38f; rl[j] = 0.f; oacc[j] = (f32x4){0.f,0.f,0.f,0.f}; }

    const int sr_ = t >> 2;
    const int sc_ = (t & 3) * 8;
    const bf16_t* Krow = Kb + ((size_t)bh * 1024 + sr_) * 64 + sc_;
    const bf16_t* Vrow = Vb + ((size_t)bh * 64 + sr_) * 1024 + sc_;

    for (int tt = 0; tt < 16; ++tt) {
        const int nk0 = tt * 64;
        bf16x8 kv0 = *(const bf16x8*)(Krow + (size_t)nk0 * 64);
        bf16x8 kv1 = *(const bf16x8*)(Krow + (size_t)nk0 * 64 + 32);
        bf16x8 vv0 = *(const bf16x8*)(Vrow + nk0);
        bf16x8 vv1 = *(const bf16x8*)(Vrow + nk0 + 32);
        __syncthreads();
        *(bf16x8*)&Ks[sr_][sc_]      = kv0;
        *(bf16x8*)&Ks[sr_][sc_ + 32] = kv1;
        *(bf16x8*)&Vs[sr_][sc_]      = vv0;
        *(bf16x8*)&Vs[sr_][sc_ + 32] = vv1;
        __syncthreads();

        // S = (Q*scale) K^T + bias   (rows = q, cols = nk)
        f32x4 s[4];
#pragma unroll
        for (int ns = 0; ns < 4; ++ns) {
            f32x4 z;
            if (PRE) {
                const bf16x4 bv = *(const bf16x4*)(bb + (size_t)(((nk0 >> 4) + ns) * 64 + l) * 4);
                z = (f32x4){(float)bv[0], (float)bv[1], (float)bv[2], (float)bv[3]};
            } else {
                z = (f32x4){0.f, 0.f, 0.f, 0.f};
            }
            const bf16x8 kf0 = *(const bf16x8*)&Ks[ns * 16 + lrow][lgrp * 8];
            const bf16x8 kf1 = *(const bf16x8*)&Ks[ns * 16 + lrow][32 + lgrp * 8];
            z = MFMA16(qf0, kf0, z);
            z = MFMA16(qf1, kf1, z);
            s[ns] = z;
        }
        if (!PRE) {
#pragma unroll
            for (int ns = 0; ns < 4; ++ns) {
                const int nk = nk0 + ns * 16 + lrow;
                const int ky = nk >> 5, kx = nk & 31;
#pragma unroll
                for (int j = 0; j < 4; ++j) {
                    const int q = q0 + w * 16 + lgrp * 4 + j;
                    const int dy = (q >> 5) - ky + 31, dx = (q & 31) - kx + 31;
                    s[ns][j] += (float)pos_s[dy * 63 + dx];
                }
            }
        }
        float tmax[4] = {-3e38f, -3e38f, -3e38f, -3e38f};
#pragma unroll
        for (int ns = 0; ns < 4; ++ns)
#pragma unroll
            for (int j = 0; j < 4; ++j) tmax[j] = fmaxf(tmax[j], s[ns][j]);
#pragma unroll
        for (int j = 0; j < 4; ++j) {
            float v = tmax[j];
            v = fmaxf(v, __shfl_xor(v, 1));
            v = fmaxf(v, __shfl_xor(v, 2));
            v = fmaxf(v, __shfl_xor(v, 4));
            v = fmaxf(v, __shfl_xor(v, 8));
            tmax[j] = v;
        }
        // defer-max (T13): only rescale if max grew by > 8
#pragma unroll
        for (int j = 0; j < 4; ++j) {
            if (tmax[j] > rm[j] + 8.f) {
                const float rf = __expf(rm[j] - tmax[j]);
                rm[j] = tmax[j];
                rl[j] *= rf;
#pragma unroll
                for (int ds = 0; ds < 4; ++ds) oacc[ds][j] *= rf;
            }
        }
        float ts[4] = {0.f, 0.f, 0.f, 0.f};
#pragma unroll
        for (int ns = 0; ns < 4; ++ns)
#pragma unroll
            for (int j = 0; j < 4; ++j) {
                const float p = __expf(s[ns][j] - rm[j]);
                ts[j] += p;
                Ps[w][lgrp * 4 + j][ns * 16 + lrow] = (bf16_t)p;
            }
#pragma unroll
        for (int j = 0; j < 4; ++j) {
            float v = ts[j];
            v += __shfl_xor(v, 1);
            v += __shfl_xor(v, 2);
            v += __shfl_xor(v, 4);
            v += __shfl_xor(v, 8);
            rl[j] += v;
        }
        const bf16x8 pf0 = *(const bf16x8*)&Ps[w][lrow][lgrp * 8];
        const bf16x8 pf1 = *(const bf16x8*)&Ps[w][lrow][32 + lgrp * 8];
#pragma unroll
        for (int ds = 0; ds < 4; ++ds) {
            const bf16x8 vf0 = *(const bf16x8*)&Vs[ds * 16 + lrow][lgrp * 8];
            const bf16x8 vf1 = *(const bf16x8*)&Vs[ds * 16 + lrow][32 + lgrp * 8];
            oacc[ds] = MFMA16(pf0, vf0, oacc[ds]);
            oacc[ds] = MFMA16(pf1, vf1, oacc[ds]);
        }
    }

    const int b = bh >> 3;
#pragma unroll
    for (int ds = 0; ds < 4; ++ds) {
#pragma unroll
        for (int j = 0; j < 4; ++j) {
            const float val = oacc[ds][j] / rl[j];
            const int q = q0 + w * 16 + lgrp * 4 + j;
            const int d = ds * 16 + lrow;
            Xo[((size_t)b * 1024 + q) * 512 + h * 64 + d] = (bf16_t)val;
        }
    }
}

// ---------------------------------------------------------------------------
extern "C" void kernel_launch(void* const* d_in, const int* in_sizes, int n_in,
                              void* d_out, int out_size, void* d_ws, size_t ws_size,
                              hipStream_t stream)
{
    const float* x     = (const float*)d_in[0];
    const float* gamma = (const float*)d_in[3];
    const float* beta  = (const float*)d_in[4];
    const float* wq    = (const float*)d_in[5];
    const float* bq    = (const float*)d_in[6];
    const float* wk    = (const float*)d_in[7];
    const float* bk    = (const float*)d_in[8];
    const float* wv    = (const float*)d_in[9];
    const float* bv    = (const float*)d_in[10];
    const float* wp    = (const float*)d_in[11];
    const float* bp    = (const float*)d_in[12];
    const float* pos   = (const float*)d_in[13];
    float* out = (float*)d_out;

    size_t off = 0;
    char* wsb = (char*)d_ws;
    auto alloc = [&](size_t bytes) { char* p = wsb + off; off += bytes; return p; };
    bf16_t* Wqkv  = (bf16_t*)alloc((size_t)1536 * 512 * 2);
    bf16_t* Wp    = (bf16_t*)alloc((size_t)512 * 512 * 2);
    bf16_t* xnT   = (bf16_t*)alloc((size_t)8192 * 512 * 2);
    bf16_t* Qb    = (bf16_t*)alloc((size_t)8192 * 512 * 2);
    bf16_t* Kb    = (bf16_t*)alloc((size_t)8192 * 512 * 2);
    bf16_t* Vb    = (bf16_t*)alloc((size_t)8192 * 512 * 2);
    bf16_t* Xo    = (bf16_t*)alloc((size_t)8192 * 512 * 2);
    bf16_t* Bias2 = (bf16_t*)alloc((size_t)8 * 64 * 64 * 64 * 4 * 2);
    const bool pre = (ws_size >= off);

    hipLaunchKernelGGL(cast_weights, dim3(256), dim3(256), 0, stream,
                       wq, wk, wv, wp, Wqkv, Wp);
    if (pre)
        hipLaunchKernelGGL(bias_kernel, dim3(512), dim3(256), 0, stream, pos, Bias2);
    hipLaunchKernelGGL(gn_kernel, dim3(256), dim3(256), 0, stream,
                       x, gamma, beta, xnT);
    hipLaunchKernelGGL(gemm_bt, dim3(12, 64), dim3(256), 0, stream,
                       Wqkv, xnT, 0, bq, bk, bv,
                       nullptr, nullptr, Qb, Kb, Vb);
    if (pre)
        attn_kernel<1><<<dim3(16, 64), dim3(256), 0, stream>>>(Qb, Kb, Vb, pos, Bias2, Xo);
    else
        attn_kernel<0><<<dim3(16, 64), dim3(256), 0, stream>>>(Qb, Kb, Vb, pos, Bias2, Xo);
    hipLaunchKernelGGL(gemm_bt, dim3(4, 64), dim3(256), 0, stream,
                       Wp, Xo, 1, bp, nullptr, nullptr,
                       x, out, nullptr, nullptr, nullptr);
}

// Round 3
// 146.390 us; speedup vs baseline: 1.2206x; 1.1749x over previous
//
#include <hip/hip_runtime.h>
#include <hip/hip_bf16.h>
#include <math.h>

typedef __bf16 bf16_t;
typedef __bf16 bf16x8 __attribute__((ext_vector_type(8)));
typedef __bf16 bf16x4 __attribute__((ext_vector_type(4)));
typedef float  f32x4  __attribute__((ext_vector_type(4)));

#define MFMA16(a, b, c) __builtin_amdgcn_mfma_f32_16x16x32_bf16((a), (b), (c), 0, 0, 0)
#define GLDS16(g, s) __builtin_amdgcn_global_load_lds( \
    (const __attribute__((address_space(1))) void*)(g), \
    (__attribute__((address_space(3))) void*)(s), 16, 0, 0)

#define LOG2E 1.4426950408889634f

// ---------------------------------------------------------------------------
// K0: cast weights fp32 -> bf16.  Wqkv = [wq; wk; wv] (1536 x 512), Wp (512x512)
// ---------------------------------------------------------------------------
__global__ __launch_bounds__(256) void cast_weights(
    const float* __restrict__ wq, const float* __restrict__ wk,
    const float* __restrict__ wv, const float* __restrict__ wp,
    bf16_t* __restrict__ Wqkv, bf16_t* __restrict__ Wp)
{
    const int i = (blockIdx.x * 256 + threadIdx.x) * 4;
#pragma unroll
    for (int j = 0; j < 4; ++j) {
        Wqkv[i + j]          = (bf16_t)wq[i + j];
        Wqkv[262144 + i + j] = (bf16_t)wk[i + j];
        Wqkv[524288 + i + j] = (bf16_t)wv[i + j];
        Wp[i + j]            = (bf16_t)wp[i + j];
    }
}

// ---------------------------------------------------------------------------
// K0b: rel-bias precompute in SWAPPED MFMA C-fragment order (D[row=nk][col=q]):
//   Bias2[h][qt(64)][kt(64)][lane(64)][j(4)]  bf16, pre-scaled by log2(e)
// q  = qt*16 + (lane&15),  nk = kt*16 + (lane>>4)*4 + j.
// ---------------------------------------------------------------------------
__global__ __launch_bounds__(256) void bias_kernel(
    const float* __restrict__ pos, bf16_t* __restrict__ Bias2)
{
    const int h   = blockIdx.x >> 6;
    const int qt  = blockIdx.x & 63;
    const int qy  = qt >> 1;
    const int qxb = (qt & 1) * 16;
    const int t = threadIdx.x;
    __shared__ bf16_t ps[32][64];   // rows dy = qy..qy+31, cols dx 0..62

    for (int i = t; i < 32 * 63; i += 256) {
        const int r = i / 63, dx = i - r * 63;
        ps[r][dx] = (bf16_t)(pos[h * 3969 + (qy + r) * 63 + dx] * LOG2E);
    }
    __syncthreads();

    bf16_t* outb = Bias2 + (((size_t)h * 64 + qt) * 64) * 256;
#pragma unroll
    for (int it = 0; it < 16; ++it) {
        const int idx = t + it * 256;        // [0, 4096) = kt*64 + lane
        const int kt = idx >> 6, l = idx & 63;
        const int qx  = qxb + (l & 15);      // col = q
        const int nk0 = kt * 16 + (l >> 4) * 4;
        const int ky = nk0 >> 5;             // j<=3 never crosses a 32-block
        const int kx0 = nk0 & 31;
        const int r = 31 - ky;
        const int dx0 = qx - kx0 + 31;
        bf16x4 o;
#pragma unroll
        for (int j = 0; j < 4; ++j) o[j] = ps[r][dx0 - j];
        *(bf16x4*)(outb + (size_t)idx * 4) = o;
    }
}

// ---------------------------------------------------------------------------
// K1: GroupNorm -> xnT[(b*1024+n)*512 + c]  (bf16, k-contiguous for GEMM)
// ---------------------------------------------------------------------------
__global__ __launch_bounds__(256) void gn_kernel(
    const float* __restrict__ x, const float* __restrict__ gamma,
    const float* __restrict__ beta, bf16_t* __restrict__ xnT)
{
    const int blk = blockIdx.x;
    const int b = blk >> 5, g = blk & 31;
    const int t = threadIdx.x;
    __shared__ float red[8];
    const float* base = x + ((size_t)b * 512 + g * 16) * 1024;

    float s = 0.f, s2 = 0.f;
    for (int i = t; i < 16384; i += 256) {
        float v = base[i];
        s += v; s2 += v * v;
    }
#pragma unroll
    for (int m = 1; m < 64; m <<= 1) { s += __shfl_xor(s, m); s2 += __shfl_xor(s2, m); }
    const int w = t >> 6;
    if ((t & 63) == 0) { red[w] = s; red[4 + w] = s2; }
    __syncthreads();
    s  = red[0] + red[1] + red[2] + red[3];
    s2 = red[4] + red[5] + red[6] + red[7];
    const float mean = s * (1.f / 16384.f);
    const float var  = fmaxf(s2 * (1.f / 16384.f) - mean * mean, 0.f);
    const float rstd = rsqrtf(var + 1e-6f);

    for (int i = t; i < 16384; i += 256) {
        const int n = i >> 4, c = i & 15;
        const float v = base[c * 1024 + n];
        const int gc = g * 16 + c;
        const float y = (v - mean) * rstd * gamma[gc] + beta[gc];
        xnT[((size_t)b * 1024 + n) * 512 + gc] = (bf16_t)y;
    }
}

// ---------------------------------------------------------------------------
// K2/K4: GEMM  C[m][n'] = sum_k A[m][k] * Bt[n'][k],  K = 512, N' = 8192.
// 128x128 tile, BK=32, global_load_lds(16B) staging into LINEAR LDS [128][32].
// mode 0: QKV epilogue (+bias; Q pre-scaled by 0.125*log2e; scatter Q/K/V)
// mode 1: proj epilogue (+bproj + x0 residual, fp32 out)
// ---------------------------------------------------------------------------
__global__ __launch_bounds__(256) void gemm_bt(
    const bf16_t* __restrict__ A, const bf16_t* __restrict__ Bt, int mode,
    const float* __restrict__ bias0, const float* __restrict__ bias1,
    const float* __restrict__ bias2,
    const float* __restrict__ x0, float* __restrict__ outF,
    bf16_t* __restrict__ Qb, bf16_t* __restrict__ Kb, bf16_t* __restrict__ Vb)
{
    const int K  = 512;
    const int m0 = blockIdx.x * 128;
    const int n0 = blockIdx.y * 128;
    const int t = threadIdx.x;
    const int l = t & 63, w = t >> 6;
    const int wr = w >> 1, wc = w & 1;
    const int lrow = l & 15, lgrp = l >> 4;

    __shared__ __align__(16) bf16_t AsF[128 * 32];   // linear, no pad (glds)
    __shared__ __align__(16) bf16_t BsF[128 * 32];

    f32x4 acc[4][4];
#pragma unroll
    for (int i = 0; i < 4; ++i)
#pragma unroll
        for (int j = 0; j < 4; ++j) acc[i][j] = (f32x4){0.f, 0.f, 0.f, 0.f};

    // staging: per wave, instr covers 16 rows x 32 cols; lane l -> row l>>2,
    // col (l&3)*8; LDS dst = base + l*16B (linear requirement of glds).
    const bf16_t* gA0 = A  + (size_t)(m0 + w * 16 + (l >> 2)) * K + (l & 3) * 8;
    const bf16_t* gA1 = gA0 + (size_t)64 * K;
    const bf16_t* gB0 = Bt + (size_t)(n0 + w * 16 + (l >> 2)) * K + (l & 3) * 8;
    const bf16_t* gB1 = gB0 + (size_t)64 * K;
    bf16_t* lA0 = &AsF[w * 512];
    bf16_t* lA1 = &AsF[2048 + w * 512];
    bf16_t* lB0 = &BsF[w * 512];
    bf16_t* lB1 = &BsF[2048 + w * 512];

    for (int k0 = 0; k0 < K; k0 += 32) {
        __syncthreads();                    // prev frag reads done
        GLDS16(gA0 + k0, lA0);
        GLDS16(gA1 + k0, lA1);
        GLDS16(gB0 + k0, lB0);
        GLDS16(gB1 + k0, lB1);
        __syncthreads();                    // drains vmcnt -> LDS ready
        bf16x8 af[4], bfr[4];
#pragma unroll
        for (int ms = 0; ms < 4; ++ms)
            af[ms] = *(const bf16x8*)&AsF[(wr * 64 + ms * 16 + lrow) * 32 + lgrp * 8];
#pragma unroll
        for (int ns = 0; ns < 4; ++ns)
            bfr[ns] = *(const bf16x8*)&BsF[(wc * 64 + ns * 16 + lrow) * 32 + lgrp * 8];
#pragma unroll
        for (int ms = 0; ms < 4; ++ms)
#pragma unroll
            for (int ns = 0; ns < 4; ++ns)
                acc[ms][ns] = MFMA16(af[ms], bfr[ns], acc[ms][ns]);
    }

    if (mode == 0) {
        const int which = m0 >> 9;    // 0=q 1=k 2=v
        const float* bias = (which == 0) ? bias0 : (which == 1) ? bias1 : bias2;
        bf16_t* Qk = (which == 0) ? Qb : Kb;
        const float scl = (which == 0) ? 0.125f * LOG2E : 1.0f;
#pragma unroll
        for (int ms = 0; ms < 4; ++ms) {
#pragma unroll
            for (int ns = 0; ns < 4; ++ns) {
                const int gm = m0 + wr * 64 + ms * 16 + lgrp * 4;
                const int o  = gm & 511;
                const int hh = o >> 6, db = o & 63;
                const int np = n0 + wc * 64 + ns * 16 + lrow;
                const int b = np >> 10, n = np & 1023;
                if (which < 2) {
                    bf16x4 pk;
#pragma unroll
                    for (int j = 0; j < 4; ++j)
                        pk[j] = (bf16_t)((acc[ms][ns][j] + bias[o + j]) * scl);
                    *(bf16x4*)(Qk + (((size_t)b * 8 + hh) * 1024 + n) * 64 + db) = pk;
                } else {
#pragma unroll
                    for (int j = 0; j < 4; ++j)
                        Vb[(((size_t)b * 8 + hh) * 64 + db + j) * 1024 + n] =
                            (bf16_t)(acc[ms][ns][j] + bias[o + j]);
                }
            }
        }
    } else {
#pragma unroll
        for (int ms = 0; ms < 4; ++ms) {
#pragma unroll
            for (int ns = 0; ns < 4; ++ns) {
                const int c  = m0 + wr * 64 + ms * 16 + lgrp * 4;
                const int np = n0 + wc * 64 + ns * 16 + lrow;
                const int b = np >> 10, n = np & 1023;
#pragma unroll
                for (int j = 0; j < 4; ++j) {
                    const size_t idx = ((size_t)b * 512 + c + j) * 1024 + n;
                    outF[idx] = acc[ms][ns][j] + bias0[c + j] + x0[idx];
                }
            }
        }
    }
}

// ---------------------------------------------------------------------------
// K3: fused attention, SWAPPED-QK + max-free base-2 softmax.
// mfma(K,Q): D[row=nk][col=q] -> every lane's 16 S-values share one q row.
// p = exp2(s) (Q,bias pre-scaled by log2e); ts = per-lane scalar, reduced
// across lgrp once at the end.  P -> per-wave LDS [q][nk] via b64 writes,
// read back as PV B-fragment; out^T = V^T * P^T gives vectored bf16x4 stores.
// ---------------------------------------------------------------------------
template <int PRE>
__global__ __launch_bounds__(256) void attn_kernel(
    const bf16_t* __restrict__ Qb, const bf16_t* __restrict__ Kb,
    const bf16_t* __restrict__ Vb, const float* __restrict__ pos,
    const bf16_t* __restrict__ Bias2, bf16_t* __restrict__ Xo)
{
    const int bh = blockIdx.y;
    const int h  = bh & 7;
    const int q0 = blockIdx.x * 64;
    const int t = threadIdx.x;
    const int w = t >> 6, l = t & 63;
    const int lrow = l & 15, lgrp = l >> 4;

    __shared__ __align__(16) bf16_t Ks[64][72];      // [nk][d]
    __shared__ __align__(16) bf16_t Vs[64][72];      // [d][nk]
    __shared__ __align__(16) bf16_t Ps[4][16][72];   // per-wave [q][nk]
    __shared__ bf16_t pos_s[PRE ? 1 : 3969];

    if (!PRE)
        for (int i = t; i < 3969; i += 256)
            pos_s[i] = (bf16_t)(pos[h * 3969 + i] * LOG2E);

    // Q fragment (B-operand now): col = lane&15 = q, k-chunk = d = lgrp*8
    const int qrow = q0 + w * 16 + lrow;
    const bf16_t* qbase = Qb + ((size_t)bh * 1024 + qrow) * 64;
    const bf16x8 qf0 = *(const bf16x8*)(qbase + lgrp * 8);
    const bf16x8 qf1 = *(const bf16x8*)(qbase + 32 + lgrp * 8);

    const bf16_t* bb = Bias2 + (((size_t)h * 64 + (q0 >> 4) + w) * 64) * 256;

    float ts = 0.f;
    f32x4 oacc[4];
#pragma unroll
    for (int j = 0; j < 4; ++j) oacc[j] = (f32x4){0.f, 0.f, 0.f, 0.f};

    const int sr_ = t >> 2;
    const int sc_ = (t & 3) * 8;
    const bf16_t* Krow = Kb + ((size_t)bh * 1024 + sr_) * 64 + sc_;
    const bf16_t* Vrow = Vb + ((size_t)bh * 64 + sr_) * 1024 + sc_;

    for (int tt = 0; tt < 16; ++tt) {
        const int nk0 = tt * 64;
        bf16x8 kv0 = *(const bf16x8*)(Krow + (size_t)nk0 * 64);
        bf16x8 kv1 = *(const bf16x8*)(Krow + (size_t)nk0 * 64 + 32);
        bf16x8 vv0 = *(const bf16x8*)(Vrow + nk0);
        bf16x8 vv1 = *(const bf16x8*)(Vrow + nk0 + 32);
        __syncthreads();
        *(bf16x8*)&Ks[sr_][sc_]      = kv0;
        *(bf16x8*)&Ks[sr_][sc_ + 32] = kv1;
        *(bf16x8*)&Vs[sr_][sc_]      = vv0;
        *(bf16x8*)&Vs[sr_][sc_ + 32] = vv1;
        __syncthreads();

        // S^T = K Q^T (+bias):  D[row = nk_local][col = q]
        f32x4 s[4];
#pragma unroll
        for (int ns = 0; ns < 4; ++ns) {
            f32x4 z;
            if (PRE) {
                const bf16x4 bv = *(const bf16x4*)(bb + (size_t)(((nk0 >> 4) + ns) * 64 + l) * 4);
                z = (f32x4){(float)bv[0], (float)bv[1], (float)bv[2], (float)bv[3]};
            } else {
                z = (f32x4){0.f, 0.f, 0.f, 0.f};
            }
            const bf16x8 kf0 = *(const bf16x8*)&Ks[ns * 16 + lrow][lgrp * 8];
            const bf16x8 kf1 = *(const bf16x8*)&Ks[ns * 16 + lrow][32 + lgrp * 8];
            z = MFMA16(kf0, qf0, z);
            z = MFMA16(kf1, qf1, z);
            s[ns] = z;
        }
        if (!PRE) {
            const int q = q0 + w * 16 + lrow;
#pragma unroll
            for (int ns = 0; ns < 4; ++ns)
#pragma unroll
                for (int j = 0; j < 4; ++j) {
                    const int nk = nk0 + ns * 16 + lgrp * 4 + j;
                    const int dy = (q >> 5) - (nk >> 5) + 31;
                    const int dx = (q & 31) - (nk & 31) + 31;
                    s[ns][j] += (float)pos_s[dy * 63 + dx];
                }
        }
        // p = exp2(s); scalar ts accumulate; pack to Ps[q][nk]
#pragma unroll
        for (int ns = 0; ns < 4; ++ns) {
            float p0 = exp2f(s[ns][0]), p1 = exp2f(s[ns][1]);
            float p2 = exp2f(s[ns][2]), p3 = exp2f(s[ns][3]);
            ts += (p0 + p1) + (p2 + p3);
            bf16x4 pk;
            pk[0] = (bf16_t)p0; pk[1] = (bf16_t)p1;
            pk[2] = (bf16_t)p2; pk[3] = (bf16_t)p3;
            *(bf16x4*)&Ps[w][lrow][ns * 16 + lgrp * 4] = pk;
        }
        // PV:  out^T[d][q] += V^T[d][nk] * P^T[nk][q]
        const bf16x8 pf0 = *(const bf16x8*)&Ps[w][lrow][lgrp * 8];
        const bf16x8 pf1 = *(const bf16x8*)&Ps[w][lrow][32 + lgrp * 8];
#pragma unroll
        for (int ds = 0; ds < 4; ++ds) {
            const bf16x8 vf0 = *(const bf16x8*)&Vs[ds * 16 + lrow][lgrp * 8];
            const bf16x8 vf1 = *(const bf16x8*)&Vs[ds * 16 + lrow][32 + lgrp * 8];
            oacc[ds] = MFMA16(vf0, pf0, oacc[ds]);
            oacc[ds] = MFMA16(vf1, pf1, oacc[ds]);
        }
    }

    // final: sum ts across the 4 lane-groups (same q), normalize, store
    ts += __shfl_xor(ts, 16);
    ts += __shfl_xor(ts, 32);
    const float inv = 1.0f / ts;

    const int b = bh >> 3;
    const int q = q0 + w * 16 + lrow;
    bf16_t* xrow = Xo + ((size_t)b * 1024 + q) * 512 + h * 64;
#pragma unroll
    for (int ds = 0; ds < 4; ++ds) {
        bf16x4 o4;
#pragma unroll
        for (int j = 0; j < 4; ++j) o4[j] = (bf16_t)(oacc[ds][j] * inv);
        *(bf16x4*)(xrow + ds * 16 + lgrp * 4) = o4;
    }
}

// ---------------------------------------------------------------------------
extern "C" void kernel_launch(void* const* d_in, const int* in_sizes, int n_in,
                              void* d_out, int out_size, void* d_ws, size_t ws_size,
                              hipStream_t stream)
{
    const float* x     = (const float*)d_in[0];
    const float* gamma = (const float*)d_in[3];
    const float* beta  = (const float*)d_in[4];
    const float* wq    = (const float*)d_in[5];
    const float* bq    = (const float*)d_in[6];
    const float* wk    = (const float*)d_in[7];
    const float* bk    = (const float*)d_in[8];
    const float* wv    = (const float*)d_in[9];
    const float* bv    = (const float*)d_in[10];
    const float* wp    = (const float*)d_in[11];
    const float* bp    = (const float*)d_in[12];
    const float* pos   = (const float*)d_in[13];
    float* out = (float*)d_out;

    size_t off = 0;
    char* wsb = (char*)d_ws;
    auto alloc = [&](size_t bytes) { char* p = wsb + off; off += bytes; return p; };
    bf16_t* Wqkv  = (bf16_t*)alloc((size_t)1536 * 512 * 2);
    bf16_t* Wp    = (bf16_t*)alloc((size_t)512 * 512 * 2);
    bf16_t* xnT   = (bf16_t*)alloc((size_t)8192 * 512 * 2);
    bf16_t* Qb    = (bf16_t*)alloc((size_t)8192 * 512 * 2);
    bf16_t* Kb    = (bf16_t*)alloc((size_t)8192 * 512 * 2);
    bf16_t* Vb    = (bf16_t*)alloc((size_t)8192 * 512 * 2);
    bf16_t* Xo    = (bf16_t*)alloc((size_t)8192 * 512 * 2);
    bf16_t* Bias2 = (bf16_t*)alloc((size_t)8 * 64 * 64 * 64 * 4 * 2);
    const bool pre = (ws_size >= off);

    hipLaunchKernelGGL(cast_weights, dim3(256), dim3(256), 0, stream,
                       wq, wk, wv, wp, Wqkv, Wp);
    if (pre)
        hipLaunchKernelGGL(bias_kernel, dim3(512), dim3(256), 0, stream, pos, Bias2);
    hipLaunchKernelGGL(gn_kernel, dim3(256), dim3(256), 0, stream,
                       x, gamma, beta, xnT);
    hipLaunchKernelGGL(gemm_bt, dim3(12, 64), dim3(256), 0, stream,
                       Wqkv, xnT, 0, bq, bk, bv,
                       nullptr, nullptr, Qb, Kb, Vb);
    if (pre)
        attn_kernel<1><<<dim3(16, 64), dim3(256), 0, stream>>>(Qb, Kb, Vb, pos, Bias2, Xo);
    else
        attn_kernel<0><<<dim3(16, 64), dim3(256), 0, stream>>>(Qb, Kb, Vb, pos, Bias2, Xo);
    hipLaunchKernelGGL(gemm_bt, dim3(4, 64), dim3(256), 0, stream,
                       Wp, Xo, 1, bp, nullptr, nullptr,
                       x, out, nullptr, nullptr, nullptr);
}